// Round 9
// baseline (342.116 us; speedup 1.0000x reference)
//
#include <hip/hip_runtime.h>
#include <stdint.h>

#define B_N   16384
#define S_N   256
#define NCH   8
#define P_N   (B_N * S_N)      // 4194304 positions (b,s)
#define EPS_F 1e-5f

typedef float  f32x4  __attribute__((ext_vector_type(4)));
typedef float  f32x16 __attribute__((ext_vector_type(16)));
typedef __bf16 bf16x8 __attribute__((ext_vector_type(8)));
typedef unsigned int u32x4 __attribute__((ext_vector_type(4)));

static __device__ __forceinline__ unsigned short f2bf(float f) {
  union { float f; unsigned u; } v; v.f = f;
  unsigned u = v.u;
  u += 0x7fffu + ((u >> 16) & 1u);          // RNE
  return (unsigned short)(u >> 16);
}
static __device__ __forceinline__ float bf2f(unsigned short h) {
  union { unsigned u; float f; } v; v.u = ((unsigned)h) << 16;
  return v.f;
}

typedef const __attribute__((address_space(1))) unsigned int* gas1_t;
typedef __attribute__((address_space(3))) unsigned int* las3_t;
// async global->LDS, 16B per lane; LDS dest must be linear (base + lane*16)
static __device__ __forceinline__ void gl16(const void* g, void* l) {
  __builtin_amdgcn_global_load_lds((gas1_t)(uintptr_t)g,
                                   (las3_t)(unsigned int)(uintptr_t)l, 16, 0, 0);
}

// ---------------- pass 1: per-channel stats partials + planar bf16 transpose ----------------
__global__ __launch_bounds__(256) void pass1_kernel(
    const float* __restrict__ x, unsigned short* __restrict__ xplan,
    float* __restrict__ partials)
{
  __shared__ float ps[4][32];
  const int t = threadIdx.x;
  const int q = t & 3;               // channel quad: interleaved channels 4q..4q+3
  const int pg = t >> 2;             // 0..63 position-group within tile
  float s[4] = {0.f,0.f,0.f,0.f}, ss[4] = {0.f,0.f,0.f,0.f};
  const f32x4* xv = (const f32x4*)x;

  for (int it = 0; it < 4; ++it) {
    size_t p0 = ((size_t)blockIdx.x * 4 + it) * 512 + (size_t)pg * 8;
    f32x4 v[8];
    #pragma unroll
    for (int j = 0; j < 8; ++j) v[j] = xv[(p0 + j) * 4 + q];
    #pragma unroll
    for (int j = 0; j < 8; ++j)
      #pragma unroll
      for (int k = 0; k < 4; ++k) { s[k] += v[j][k]; ss[k] += v[j][k] * v[j][k]; }
    #pragma unroll
    for (int j2 = 0; j2 < 4; ++j2) {
      u32x4 w;
      #pragma unroll
      for (int k = 0; k < 4; ++k)
        w[k] = (unsigned)f2bf(v[2*k][j2]) | ((unsigned)f2bf(v[2*k+1][j2]) << 16);
      *(u32x4*)(xplan + (size_t)(q * 4 + j2) * P_N + p0) = w;
    }
  }

  #pragma unroll
  for (int off = 32; off >= 4; off >>= 1) {
    #pragma unroll
    for (int k = 0; k < 4; ++k) { s[k] += __shfl_down(s[k], off); ss[k] += __shfl_down(ss[k], off); }
  }
  const int lane = t & 63, wid = t >> 6;
  if (lane < 4) {
    #pragma unroll
    for (int k = 0; k < 4; ++k) {
      ps[wid][lane * 4 + k]      = s[k];
      ps[wid][16 + lane * 4 + k] = ss[k];
    }
  }
  __syncthreads();
  if (t < 32)
    partials[blockIdx.x * 32 + t] = ps[0][t] + ps[1][t] + ps[2][t] + ps[3][t];
}

// ---------------- finalize: reduce partials -> A,C ----------------
__global__ __launch_bounds__(1024) void finalize_kernel(
    const float* __restrict__ partials, const float* __restrict__ g_in,
    const float* __restrict__ b_in, float* __restrict__ AC)
{
  __shared__ float acc[32][32];
  const int t = threadIdx.x;
  const int v = t & 31, chunk = t >> 5;
  float s = 0.f;
  for (int i = 0; i < 64; ++i)
    s += partials[(size_t)(chunk * 64 + i) * 32 + v];
  acc[chunk][v] = s;
  __syncthreads();
  if (t < 32) {
    float tot = 0.f;
    #pragma unroll
    for (int k = 0; k < 32; ++k) tot += acc[k][t];
    acc[0][t] = tot;
  }
  __syncthreads();
  if (t < 16) {
    float n = (float)P_N;
    float mu  = acc[0][t] / n;
    float var = acc[0][16 + t] / n - mu * mu;
    float A = g_in[t] * rsqrtf(var + EPS_F);
    AC[t] = A;
    AC[16 + t] = b_in[t] - mu * A;
  }
}

// ---------------- W prep: fp32 -> bf16, per-wave-register-fragment layout + rowsums -------------
// wrp/wip[c][ow8][u16][kh2][o31:32][j8]: a wave's wreg[u] load = two contiguous 512B runs.
__global__ __launch_bounds__(256) void wprep_kernel(
    const float* __restrict__ Wr, const float* __restrict__ Wi,
    unsigned short* __restrict__ wrp, unsigned short* __restrict__ wip,
    float* __restrict__ RWr, float* __restrict__ RWi)
{
  __shared__ float sr[4], si[4];
  const int row = blockIdx.x, t = threadIdx.x;   // row = c*256 + o, t = k
  const int c = row >> 8, o = row & 255;
  const int ow = o >> 5, o31 = o & 31;
  const size_t idx = (size_t)row * 256 + t;
  float vr = Wr[idx], vi = Wi[idx];
  const int u = t >> 4, kh = (t >> 3) & 1, j = t & 7;
  const size_t widx = ((((size_t)(c * 8 + ow) * 16 + u) * 2 + kh) * 32 + o31) * 8 + j;
  wrp[widx] = f2bf(vr);
  wip[widx] = f2bf(vi);
  float rr = vr, ri = vi;
  #pragma unroll
  for (int off = 32; off >= 1; off >>= 1) { rr += __shfl_down(rr, off); ri += __shfl_down(ri, off); }
  if ((t & 63) == 0) { sr[t >> 6] = rr; si[t >> 6] = ri; }
  __syncthreads();
  if (t == 0) {
    RWr[row] = sr[0] + sr[1] + sr[2] + sr[3];
    RWi[row] = si[0] + si[1] + si[2] + si[3];
  }
}

// ---------------- K terms ----------------
__global__ __launch_bounds__(256) void kterm_kernel(
    const float* __restrict__ AC, const float* __restrict__ RWr, const float* __restrict__ RWi,
    float* __restrict__ Kr, float* __restrict__ Ki)
{
  int idx = blockIdx.x * 256 + threadIdx.x;   // 2048 = c*256+o
  int c = idx >> 8;
  float Ci_ = AC[16 + 2*c], Cq_ = AC[16 + 2*c + 1];
  Kr[idx] = Ci_ * RWr[idx] - Cq_ * RWi[idx];
  Ki[idx] = Cq_ * RWr[idx] + Ci_ * RWi[idx];
}

// X tile stage: 32 rows x 256 k x 2 planes = 32 KB; 4 gl16/thread (512 thr);
// LDS slot s of row r holds granule g = s ^ r (full 5-bit XOR).
static __device__ __forceinline__ void stage_x(
    const unsigned short* __restrict__ xplan, int c, int r0, char* buf, int t)
{
  #pragma unroll
  for (int i = 0; i < 4; ++i) {
    const int rowp = i * 16 + (t >> 5);       // 0..63 = plane*32 + row
    const int pl = rowp >> 5, row = rowp & 31;
    const int g = (t & 31) ^ row;             // data granule at this slot
    const char* gsrc = (const char*)xplan +
      (((size_t)(2 * c + pl) * P_N + (size_t)(r0 + row) * 256 + g * 8) << 1);
    gl16(gsrc, buf + i * 8192 + t * 16);      // linear: wave-uniform base + lane*16
  }
}

// ---------------- main: FLIPPED mfma(A=W, B=X): C/D col = b -> o-reduction is in-lane ---------
// grid 512 = 8 channels x 64 row-groups; block 512 thr (8 waves; wave w owns o-tile w);
// W resident in 128 VGPRs per wave; X streamed via dbuf LDS; 1 __syncthreads per 32-b tile.
__global__ __launch_bounds__(512, 2) void main_kernel(
    const unsigned short* __restrict__ xplan,
    const unsigned short* __restrict__ wrp,
    const unsigned short* __restrict__ wip,
    const float* __restrict__ AC,
    const float* __restrict__ Kr, const float* __restrict__ Ki,
    const float* __restrict__ Wfr, const float* __restrict__ Wfi,
    float* __restrict__ pacc)
{
  __shared__ char X[2][32768];
  __shared__ float red[8][32][2];

  const int t = threadIdx.x;
  const int w = t >> 6, lane = t & 63;
  const int l31 = lane & 31, kh = lane >> 5;   // l31: A-row (o) for W load, B-col (b) for X/epilogue
  const int c = blockIdx.x & 7;
  const int b0 = (blockIdx.x >> 3) * 256;

  const float Ai = AC[2*c], Aq = AC[2*c + 1];
  const float Ci = AC[16 + 2*c], Cq = AC[16 + 2*c + 1];

  // per-q epilogue coefficients: o(q) = w*32 + (q&3)+8*(q>>2)+4*kh  (constant per lane)
  float kr[16], ki[16], fr[16], fi[16];
  #pragma unroll
  for (int q = 0; q < 16; ++q) {
    const int o = w * 32 + (q & 3) + 8 * (q >> 2) + 4 * kh;
    const int gidx = c * 256 + o;
    kr[q] = Kr[gidx]; ki[q] = Ki[gidx];
    fr[q] = Wfr[gidx]; fi[q] = Wfi[gidx];
  }

  // ---- W into registers (A-operand: row = o = w*32 + l31) ----
  bf16x8 wr8[16], wi8[16];
  {
    const char* wb  = (const char*)wrp + (size_t)(c * 8 + w) * 16384 + kh * 512 + l31 * 16;
    const char* wib = (const char*)wip + (size_t)(c * 8 + w) * 16384 + kh * 512 + l31 * 16;
    #pragma unroll
    for (int u = 0; u < 16; ++u) {
      wr8[u] = *(const bf16x8*)(wb  + u * 1024);
      wi8[u] = *(const bf16x8*)(wib + u * 1024);
    }
  }

  stage_x(xplan, c, b0, X[0], t);
  __syncthreads();                    // stage(0) drained (vmcnt 0 + barrier)

  #pragma unroll 1
  for (int tile = 0; tile < 8; ++tile) {
    if (tile + 1 < 8)
      stage_x(xplan, c, b0 + (tile + 1) * 32, X[(tile + 1) & 1], t);  // prefetch, in flight

    const char* Xb = (const char*)X[tile & 1];
    f32x16 arr, aqr, ari, aqi;        // [o-row(q)][b-col=l31]: Srr, Sqr, Sii, Sqi
    #pragma unroll
    for (int e = 0; e < 16; ++e) { arr[e]=0.f; aqr[e]=0.f; ari[e]=0.f; aqi[e]=0.f; }

    __builtin_amdgcn_s_setprio(1);
    #pragma unroll
    for (int u = 0; u < 16; ++u) {
      const int ga = (((u * 2 + kh) ^ l31) << 4);
      bf16x8 xi8 = *(const bf16x8*)(Xb + l31 * 512 + ga);
      bf16x8 xq8 = *(const bf16x8*)(Xb + 16384 + l31 * 512 + ga);
      arr = __builtin_amdgcn_mfma_f32_32x32x16_bf16(wr8[u], xi8, arr, 0,0,0);
      aqr = __builtin_amdgcn_mfma_f32_32x32x16_bf16(wr8[u], xq8, aqr, 0,0,0);
      ari = __builtin_amdgcn_mfma_f32_32x32x16_bf16(wi8[u], xi8, ari, 0,0,0);
      aqi = __builtin_amdgcn_mfma_f32_32x32x16_bf16(wi8[u], xq8, aqi, 0,0,0);
    }
    __builtin_amdgcn_s_setprio(0);

    // epilogue: amp2 fold + K/Wf coefficients; o-reduction is IN-LANE (sum over q)
    float pC0 = 0.f, pC1 = 0.f;
    #pragma unroll
    for (int q = 0; q < 16; ++q) {
      const int o = w * 32 + (q & 3) + 8 * (q >> 2) + 4 * kh;
      const int sb = l31 * 512 + (((o >> 3) ^ l31) << 4) + (o & 7) * 2;
      float xiv = Ai * bf2f(*(const unsigned short*)(Xb + sb)) + Ci;
      float xqv = Aq * bf2f(*(const unsigned short*)(Xb + 16384 + sb)) + Cq;
      float amp = xiv * xiv + xqv * xqv;
      float cr  = Ai * arr[q] - Aq * aqi[q] + kr[q];
      float ci_ = Aq * aqr[q] + Ai * ari[q] + ki[q];
      pC0 += amp * (cr * fr[q] - ci_ * fi[q]);
      pC1 += amp * (ci_ * fr[q] + cr * fi[q]);
    }
    // combine the two kh halves (other 16 o-rows), then cross-wave via tiny LDS
    pC0 += __shfl_xor(pC0, 32);
    pC1 += __shfl_xor(pC1, 32);
    if (lane < 32) { red[w][l31][0] = pC0; red[w][l31][1] = pC1; }

    __syncthreads();   // red visible; stage(tile+1) drained; buf swap safe
    if (t < 64) {
      const int row = t >> 1, cc = t & 1;
      float v = 0.f;
      #pragma unroll
      for (int ww = 0; ww < 8; ++ww) v += red[ww][row][cc];
      pacc[((size_t)c * B_N + b0 + tile * 32 + row) * 2 + cc] = v;
    }
  }
}

// ---------------- final LN, 3 stages ----------------
__global__ __launch_bounds__(256) void ln_a_kernel(
    const float* __restrict__ pacc, float* __restrict__ y, float* __restrict__ spart)
{
  __shared__ float ws_[4][4];
  const int t = threadIdx.x;
  const int r = blockIdx.x * 256 + t;
  float v0 = 0.f, v1 = 0.f;
  #pragma unroll
  for (int c = 0; c < 8; ++c) {
    v0 += pacc[((size_t)c * B_N + r) * 2];
    v1 += pacc[((size_t)c * B_N + r) * 2 + 1];
  }
  y[r * 2] = v0; y[r * 2 + 1] = v1;
  float s0 = v0, q0 = v0 * v0, s1 = v1, q1 = v1 * v1;
  #pragma unroll
  for (int off = 32; off >= 1; off >>= 1) {
    s0 += __shfl_down(s0, off); q0 += __shfl_down(q0, off);
    s1 += __shfl_down(s1, off); q1 += __shfl_down(q1, off);
  }
  if ((t & 63) == 0) { int wv = t >> 6; ws_[wv][0]=s0; ws_[wv][1]=q0; ws_[wv][2]=s1; ws_[wv][3]=q1; }
  __syncthreads();
  if (t < 4)
    spart[blockIdx.x * 4 + t] = ws_[0][t] + ws_[1][t] + ws_[2][t] + ws_[3][t];
}

__global__ void ln_b_kernel(const float* __restrict__ spart, float* __restrict__ st)
{
  const int t = threadIdx.x;            // 64 threads
  const int q = t & 3, i0 = t >> 2;     // 16 row-groups x 4 components
  float s = 0.f;
  #pragma unroll
  for (int i = 0; i < 4; ++i) s += spart[(i0 + i * 16) * 4 + q];
  s += __shfl_down(s, 32); s += __shfl_down(s, 16);
  s += __shfl_down(s, 8);  s += __shfl_down(s, 4);
  if (t < 4) {
    float n = (float)B_N;
    float S0 = __shfl(s, 0), Q0 = __shfl(s, 1), S1 = __shfl(s, 2), Q1 = __shfl(s, 3);
    if (t == 0) {
      float mu0 = S0 / n, var0 = Q0 / n - mu0 * mu0;
      float mu1 = S1 / n, var1 = Q1 / n - mu1 * mu1;
      st[0] = mu0; st[1] = rsqrtf(var0 + EPS_F);
      st[2] = mu1; st[3] = rsqrtf(var1 + EPS_F);
    }
  }
}

__global__ __launch_bounds__(256) void ln_c_kernel(
    const float* __restrict__ y, const float* __restrict__ st,
    const float* __restrict__ g_out, const float* __restrict__ b_out,
    float* __restrict__ out)
{
  const int i = blockIdx.x * 256 + threadIdx.x;   // 32768 values
  const int cc = i & 1;
  out[i] = (y[i] - st[cc * 2]) * st[cc * 2 + 1] * g_out[cc] + b_out[cc];
}

extern "C" void kernel_launch(void* const* d_in, const int* in_sizes, int n_in,
                              void* d_out, int out_size, void* d_ws, size_t ws_size,
                              hipStream_t stream) {
  (void)in_sizes; (void)n_in; (void)out_size; (void)ws_size;
  const float* x    = (const float*)d_in[0];
  // d_in[1] = h_0 (unused by the reference)
  const float* Wr   = (const float*)d_in[2];
  const float* Wi   = (const float*)d_in[3];
  const float* Wfr  = (const float*)d_in[4];
  const float* Wfi  = (const float*)d_in[5];
  const float* g_in = (const float*)d_in[6];
  const float* b_in = (const float*)d_in[7];
  const float* g_out= (const float*)d_in[8];
  const float* b_out= (const float*)d_in[9];
  float* out = (float*)d_out;

  char* ws = (char*)d_ws;
  float* AC    = (float*)(ws + 128);              // 32 f
  float* RWr   = (float*)(ws + 256);              // 8 KB
  float* RWi   = (float*)(ws + 8448);
  float* Kr    = (float*)(ws + 16640);
  float* Ki    = (float*)(ws + 24832);
  float* spart = (float*)(ws + 33024);            // 64*4 f
  float* st    = (float*)(ws + 34048);            // 4 f
  float* y     = (float*)(ws + 36864);            // 128 KB -> 167936
  unsigned short* wrp = (unsigned short*)(ws + 167936);               // 1 MB
  unsigned short* wip = (unsigned short*)(ws + 167936 + 1048576);     // 1 MB
  float* pacc  = (float*)(ws + 2265088);          // 8*16384*2 f = 1 MB
  // pass1 partials overlap pacc (finalize consumes before main writes pacc)
  float* partials = (float*)(ws + 2265088);       // 256 KB
  unsigned short* xplan = (unsigned short*)(ws + 3313664);            // 128 MB

  pass1_kernel<<<2048, 256, 0, stream>>>(x, xplan, partials);
  finalize_kernel<<<1, 1024, 0, stream>>>(partials, g_in, b_in, AC);
  wprep_kernel<<<2048, 256, 0, stream>>>(Wr, Wi, wrp, wip, RWr, RWi);
  kterm_kernel<<<8, 256, 0, stream>>>(AC, RWr, RWi, Kr, Ki);
  main_kernel<<<512, 512, 0, stream>>>(xplan, wrp, wip, AC, Kr, Ki, Wfr, Wfi, pacc);
  ln_a_kernel<<<64, 256, 0, stream>>>(pacc, y, spart);
  ln_b_kernel<<<1, 64, 0, stream>>>(spart, st);
  ln_c_kernel<<<128, 256, 0, stream>>>(y, st, g_out, b_out, out);
}

// Round 10
// 331.798 us; speedup vs baseline: 1.0311x; 1.0311x over previous
//
#include <hip/hip_runtime.h>
#include <stdint.h>

#define B_N   16384
#define S_N   256
#define NCH   8
#define P_N   (B_N * S_N)      // 4194304 positions (b,s)
#define EPS_F 1e-5f

typedef float  f32x4  __attribute__((ext_vector_type(4)));
typedef float  f32x16 __attribute__((ext_vector_type(16)));
typedef __bf16 bf16x8 __attribute__((ext_vector_type(8)));
typedef unsigned int u32x4 __attribute__((ext_vector_type(4)));

static __device__ __forceinline__ unsigned short f2bf(float f) {
  union { float f; unsigned u; } v; v.f = f;
  unsigned u = v.u;
  u += 0x7fffu + ((u >> 16) & 1u);          // RNE
  return (unsigned short)(u >> 16);
}
static __device__ __forceinline__ float bf2f(unsigned short h) {
  union { unsigned u; float f; } v; v.u = ((unsigned)h) << 16;
  return v.f;
}

typedef const __attribute__((address_space(1))) unsigned int* gas1_t;
typedef __attribute__((address_space(3))) unsigned int* las3_t;
// async global->LDS, 16B per lane; LDS dest must be linear (base + lane*16)
static __device__ __forceinline__ void gl16(const void* g, void* l) {
  __builtin_amdgcn_global_load_lds((gas1_t)(uintptr_t)g,
                                   (las3_t)(unsigned int)(uintptr_t)l, 16, 0, 0);
}

// ---------------- pass 1: per-channel stats partials + planar bf16 transpose ----------------
__global__ __launch_bounds__(256) void pass1_kernel(
    const float* __restrict__ x, unsigned short* __restrict__ xplan,
    float* __restrict__ partials)
{
  __shared__ float ps[4][32];
  const int t = threadIdx.x;
  const int q = t & 3;               // channel quad: interleaved channels 4q..4q+3
  const int pg = t >> 2;             // 0..63 position-group within tile
  float s[4] = {0.f,0.f,0.f,0.f}, ss[4] = {0.f,0.f,0.f,0.f};
  const f32x4* xv = (const f32x4*)x;

  for (int it = 0; it < 4; ++it) {
    size_t p0 = ((size_t)blockIdx.x * 4 + it) * 512 + (size_t)pg * 8;
    f32x4 v[8];
    #pragma unroll
    for (int j = 0; j < 8; ++j) v[j] = xv[(p0 + j) * 4 + q];
    #pragma unroll
    for (int j = 0; j < 8; ++j)
      #pragma unroll
      for (int k = 0; k < 4; ++k) { s[k] += v[j][k]; ss[k] += v[j][k] * v[j][k]; }
    #pragma unroll
    for (int j2 = 0; j2 < 4; ++j2) {
      u32x4 w;
      #pragma unroll
      for (int k = 0; k < 4; ++k)
        w[k] = (unsigned)f2bf(v[2*k][j2]) | ((unsigned)f2bf(v[2*k+1][j2]) << 16);
      *(u32x4*)(xplan + (size_t)(q * 4 + j2) * P_N + p0) = w;
    }
  }

  #pragma unroll
  for (int off = 32; off >= 4; off >>= 1) {
    #pragma unroll
    for (int k = 0; k < 4; ++k) { s[k] += __shfl_down(s[k], off); ss[k] += __shfl_down(ss[k], off); }
  }
  const int lane = t & 63, wid = t >> 6;
  if (lane < 4) {
    #pragma unroll
    for (int k = 0; k < 4; ++k) {
      ps[wid][lane * 4 + k]      = s[k];
      ps[wid][16 + lane * 4 + k] = ss[k];
    }
  }
  __syncthreads();
  if (t < 32)
    partials[blockIdx.x * 32 + t] = ps[0][t] + ps[1][t] + ps[2][t] + ps[3][t];
}

// ---------------- finalize: reduce partials -> A,C ----------------
__global__ __launch_bounds__(1024) void finalize_kernel(
    const float* __restrict__ partials, const float* __restrict__ g_in,
    const float* __restrict__ b_in, float* __restrict__ AC)
{
  __shared__ float acc[32][32];
  const int t = threadIdx.x;
  const int v = t & 31, chunk = t >> 5;
  float s = 0.f;
  for (int i = 0; i < 64; ++i)
    s += partials[(size_t)(chunk * 64 + i) * 32 + v];
  acc[chunk][v] = s;
  __syncthreads();
  if (t < 32) {
    float tot = 0.f;
    #pragma unroll
    for (int k = 0; k < 32; ++k) tot += acc[k][t];
    acc[0][t] = tot;
  }
  __syncthreads();
  if (t < 16) {
    float n = (float)P_N;
    float mu  = acc[0][t] / n;
    float var = acc[0][16 + t] / n - mu * mu;
    float A = g_in[t] * rsqrtf(var + EPS_F);
    AC[t] = A;
    AC[16 + t] = b_in[t] - mu * A;
  }
}

// ---------------- W prep: fp32 -> bf16, per-wave-register-fragment layout + rowsums -------------
// wrp/wip[c][ow8][u16][kh2][o31:32][j8]: a wave's wreg[u] load = two contiguous 512B runs.
__global__ __launch_bounds__(256) void wprep_kernel(
    const float* __restrict__ Wr, const float* __restrict__ Wi,
    unsigned short* __restrict__ wrp, unsigned short* __restrict__ wip,
    float* __restrict__ RWr, float* __restrict__ RWi)
{
  __shared__ float sr[4], si[4];
  const int row = blockIdx.x, t = threadIdx.x;   // row = c*256 + o, t = k
  const int c = row >> 8, o = row & 255;
  const int ow = o >> 5, o31 = o & 31;
  const size_t idx = (size_t)row * 256 + t;
  float vr = Wr[idx], vi = Wi[idx];
  const int u = t >> 4, kh = (t >> 3) & 1, j = t & 7;
  const size_t widx = ((((size_t)(c * 8 + ow) * 16 + u) * 2 + kh) * 32 + o31) * 8 + j;
  wrp[widx] = f2bf(vr);
  wip[widx] = f2bf(vi);
  float rr = vr, ri = vi;
  #pragma unroll
  for (int off = 32; off >= 1; off >>= 1) { rr += __shfl_down(rr, off); ri += __shfl_down(ri, off); }
  if ((t & 63) == 0) { sr[t >> 6] = rr; si[t >> 6] = ri; }
  __syncthreads();
  if (t == 0) {
    RWr[row] = sr[0] + sr[1] + sr[2] + sr[3];
    RWi[row] = si[0] + si[1] + si[2] + si[3];
  }
}

// ---------------- K terms ----------------
__global__ __launch_bounds__(256) void kterm_kernel(
    const float* __restrict__ AC, const float* __restrict__ RWr, const float* __restrict__ RWi,
    float* __restrict__ Kr, float* __restrict__ Ki)
{
  int idx = blockIdx.x * 256 + threadIdx.x;   // 2048 = c*256+o
  int c = idx >> 8;
  float Ci_ = AC[16 + 2*c], Cq_ = AC[16 + 2*c + 1];
  Kr[idx] = Ci_ * RWr[idx] - Cq_ * RWi[idx];
  Ki[idx] = Cq_ * RWr[idx] + Ci_ * RWi[idx];
}

// X tile stage: 32 rows x 256 k x 2 planes = 32 KB; 4 gl16/thread (512 thr);
// LDS slot s of row r holds granule g = s ^ r (full 5-bit XOR).
static __device__ __forceinline__ void stage_x(
    const unsigned short* __restrict__ xplan, int c, int r0, char* buf, int t)
{
  #pragma unroll
  for (int i = 0; i < 4; ++i) {
    const int rowp = i * 16 + (t >> 5);       // 0..63 = plane*32 + row
    const int pl = rowp >> 5, row = rowp & 31;
    const int g = (t & 31) ^ row;             // data granule at this slot
    const char* gsrc = (const char*)xplan +
      (((size_t)(2 * c + pl) * P_N + (size_t)(r0 + row) * 256 + g * 8) << 1);
    gl16(gsrc, buf + i * 8192 + t * 16);      // linear: wave-uniform base + lane*16
  }
}

// ---------------- main: FLIPPED mfma(A=W, B=X): C/D col = b -> o-reduction is in-lane ---------
// grid 512 = 8 channels x 64 row-groups; block 512 thr (8 waves; wave w owns o-tile w);
// W resident in 128 VGPRs per wave; X streamed via dbuf LDS; 1 __syncthreads per 32-b tile.
// Coefficients (Kr/Ki/Wfr/Wfi) loaded INLINE in the epilogue (no preload arrays -> no spill).
__global__ __launch_bounds__(512, 2) void main_kernel(
    const unsigned short* __restrict__ xplan,
    const unsigned short* __restrict__ wrp,
    const unsigned short* __restrict__ wip,
    const float* __restrict__ AC,
    const float* __restrict__ Kr, const float* __restrict__ Ki,
    const float* __restrict__ Wfr, const float* __restrict__ Wfi,
    float* __restrict__ pacc)
{
  __shared__ char X[2][32768];
  __shared__ float red[8][32][2];

  const int t = threadIdx.x;
  const int w = t >> 6, lane = t & 63;
  const int l31 = lane & 31, kh = lane >> 5;   // l31: A-row (o) for W load, B-col (b) for X/epilogue
  const int c = blockIdx.x & 7;
  const int b0 = (blockIdx.x >> 3) * 256;

  const float Ai = AC[2*c], Aq = AC[2*c + 1];
  const float Ci = AC[16 + 2*c], Cq = AC[16 + 2*c + 1];

  // ---- W into registers (A-operand: row = o = w*32 + l31) ----
  bf16x8 wr8[16], wi8[16];
  {
    const char* wb  = (const char*)wrp + (size_t)(c * 8 + w) * 16384 + kh * 512 + l31 * 16;
    const char* wib = (const char*)wip + (size_t)(c * 8 + w) * 16384 + kh * 512 + l31 * 16;
    #pragma unroll
    for (int u = 0; u < 16; ++u) {
      wr8[u] = *(const bf16x8*)(wb  + u * 1024);
      wi8[u] = *(const bf16x8*)(wib + u * 1024);
    }
  }

  stage_x(xplan, c, b0, X[0], t);
  __syncthreads();                    // stage(0) drained (vmcnt 0 + barrier)

  #pragma unroll 1
  for (int tile = 0; tile < 8; ++tile) {
    if (tile + 1 < 8)
      stage_x(xplan, c, b0 + (tile + 1) * 32, X[(tile + 1) & 1], t);  // prefetch, in flight

    const char* Xb = (const char*)X[tile & 1];
    f32x16 arr, aqr, ari, aqi;        // [o-row(q)][b-col=l31]: Srr, Sqr, Sii, Sqi
    #pragma unroll
    for (int e = 0; e < 16; ++e) { arr[e]=0.f; aqr[e]=0.f; ari[e]=0.f; aqi[e]=0.f; }

    __builtin_amdgcn_s_setprio(1);
    #pragma unroll
    for (int u = 0; u < 16; ++u) {
      const int ga = (((u * 2 + kh) ^ l31) << 4);
      bf16x8 xi8 = *(const bf16x8*)(Xb + l31 * 512 + ga);
      bf16x8 xq8 = *(const bf16x8*)(Xb + 16384 + l31 * 512 + ga);
      arr = __builtin_amdgcn_mfma_f32_32x32x16_bf16(wr8[u], xi8, arr, 0,0,0);
      aqr = __builtin_amdgcn_mfma_f32_32x32x16_bf16(wr8[u], xq8, aqr, 0,0,0);
      ari = __builtin_amdgcn_mfma_f32_32x32x16_bf16(wi8[u], xi8, ari, 0,0,0);
      aqi = __builtin_amdgcn_mfma_f32_32x32x16_bf16(wi8[u], xq8, aqi, 0,0,0);
    }
    __builtin_amdgcn_s_setprio(0);

    // epilogue: amp2 fold + inline coefficient loads; o-reduction is IN-LANE (sum over q)
    float pC0 = 0.f, pC1 = 0.f;
    #pragma unroll
    for (int q = 0; q < 16; ++q) {
      const int o = w * 32 + (q & 3) + 8 * (q >> 2) + 4 * kh;
      const int gidx = c * 256 + o;
      const float kr = Kr[gidx], ki = Ki[gidx];       // L1/L2-hot, short live range
      const float fr = Wfr[gidx], fi = Wfi[gidx];
      const int sb = l31 * 512 + (((o >> 3) ^ l31) << 4) + (o & 7) * 2;
      float xiv = Ai * bf2f(*(const unsigned short*)(Xb + sb)) + Ci;
      float xqv = Aq * bf2f(*(const unsigned short*)(Xb + 16384 + sb)) + Cq;
      float amp = xiv * xiv + xqv * xqv;
      float cr  = Ai * arr[q] - Aq * aqi[q] + kr;
      float ci_ = Aq * aqr[q] + Ai * ari[q] + ki;
      pC0 += amp * (cr * fr - ci_ * fi);
      pC1 += amp * (ci_ * fr + cr * fi);
    }
    // combine the two kh halves (other 16 o-rows), then cross-wave via tiny LDS
    pC0 += __shfl_xor(pC0, 32);
    pC1 += __shfl_xor(pC1, 32);
    if (lane < 32) { red[w][l31][0] = pC0; red[w][l31][1] = pC1; }

    __syncthreads();   // red visible; stage(tile+1) drained; buf swap safe
    if (t < 64) {
      const int row = t >> 1, cc = t & 1;
      float v = 0.f;
      #pragma unroll
      for (int ww = 0; ww < 8; ++ww) v += red[ww][row][cc];
      pacc[((size_t)c * B_N + b0 + tile * 32 + row) * 2 + cc] = v;
    }
  }
}

// ---------------- final LN, 3 stages ----------------
__global__ __launch_bounds__(256) void ln_a_kernel(
    const float* __restrict__ pacc, float* __restrict__ y, float* __restrict__ spart)
{
  __shared__ float ws_[4][4];
  const int t = threadIdx.x;
  const int r = blockIdx.x * 256 + t;
  float v0 = 0.f, v1 = 0.f;
  #pragma unroll
  for (int c = 0; c < 8; ++c) {
    v0 += pacc[((size_t)c * B_N + r) * 2];
    v1 += pacc[((size_t)c * B_N + r) * 2 + 1];
  }
  y[r * 2] = v0; y[r * 2 + 1] = v1;
  float s0 = v0, q0 = v0 * v0, s1 = v1, q1 = v1 * v1;
  #pragma unroll
  for (int off = 32; off >= 1; off >>= 1) {
    s0 += __shfl_down(s0, off); q0 += __shfl_down(q0, off);
    s1 += __shfl_down(s1, off); q1 += __shfl_down(q1, off);
  }
  if ((t & 63) == 0) { int wv = t >> 6; ws_[wv][0]=s0; ws_[wv][1]=q0; ws_[wv][2]=s1; ws_[wv][3]=q1; }
  __syncthreads();
  if (t < 4)
    spart[blockIdx.x * 4 + t] = ws_[0][t] + ws_[1][t] + ws_[2][t] + ws_[3][t];
}

__global__ void ln_b_kernel(const float* __restrict__ spart, float* __restrict__ st)
{
  const int t = threadIdx.x;            // 64 threads
  const int q = t & 3, i0 = t >> 2;     // 16 row-groups x 4 components
  float s = 0.f;
  #pragma unroll
  for (int i = 0; i < 4; ++i) s += spart[(i0 + i * 16) * 4 + q];
  s += __shfl_down(s, 32); s += __shfl_down(s, 16);
  s += __shfl_down(s, 8);  s += __shfl_down(s, 4);
  if (t < 4) {
    float n = (float)B_N;
    float S0 = __shfl(s, 0), Q0 = __shfl(s, 1), S1 = __shfl(s, 2), Q1 = __shfl(s, 3);
    if (t == 0) {
      float mu0 = S0 / n, var0 = Q0 / n - mu0 * mu0;
      float mu1 = S1 / n, var1 = Q1 / n - mu1 * mu1;
      st[0] = mu0; st[1] = rsqrtf(var0 + EPS_F);
      st[2] = mu1; st[3] = rsqrtf(var1 + EPS_F);
    }
  }
}

__global__ __launch_bounds__(256) void ln_c_kernel(
    const float* __restrict__ y, const float* __restrict__ st,
    const float* __restrict__ g_out, const float* __restrict__ b_out,
    float* __restrict__ out)
{
  const int i = blockIdx.x * 256 + threadIdx.x;   // 32768 values
  const int cc = i & 1;
  out[i] = (y[i] - st[cc * 2]) * st[cc * 2 + 1] * g_out[cc] + b_out[cc];
}

extern "C" void kernel_launch(void* const* d_in, const int* in_sizes, int n_in,
                              void* d_out, int out_size, void* d_ws, size_t ws_size,
                              hipStream_t stream) {
  (void)in_sizes; (void)n_in; (void)out_size; (void)ws_size;
  const float* x    = (const float*)d_in[0];
  // d_in[1] = h_0 (unused by the reference)
  const float* Wr   = (const float*)d_in[2];
  const float* Wi   = (const float*)d_in[3];
  const float* Wfr  = (const float*)d_in[4];
  const float* Wfi  = (const float*)d_in[5];
  const float* g_in = (const float*)d_in[6];
  const float* b_in = (const float*)d_in[7];
  const float* g_out= (const float*)d_in[8];
  const float* b_out= (const float*)d_in[9];
  float* out = (float*)d_out;

  char* ws = (char*)d_ws;
  float* AC    = (float*)(ws + 128);              // 32 f
  float* RWr   = (float*)(ws + 256);              // 8 KB
  float* RWi   = (float*)(ws + 8448);
  float* Kr    = (float*)(ws + 16640);
  float* Ki    = (float*)(ws + 24832);
  float* spart = (float*)(ws + 33024);            // 64*4 f
  float* st    = (float*)(ws + 34048);            // 4 f
  float* y     = (float*)(ws + 36864);            // 128 KB -> 167936
  unsigned short* wrp = (unsigned short*)(ws + 167936);               // 1 MB
  unsigned short* wip = (unsigned short*)(ws + 167936 + 1048576);     // 1 MB
  float* pacc  = (float*)(ws + 2265088);          // 8*16384*2 f = 1 MB
  // pass1 partials overlap pacc (finalize consumes before main writes pacc)
  float* partials = (float*)(ws + 2265088);       // 256 KB
  unsigned short* xplan = (unsigned short*)(ws + 3313664);            // 128 MB

  pass1_kernel<<<2048, 256, 0, stream>>>(x, xplan, partials);
  finalize_kernel<<<1, 1024, 0, stream>>>(partials, g_in, b_in, AC);
  wprep_kernel<<<2048, 256, 0, stream>>>(Wr, Wi, wrp, wip, RWr, RWi);
  kterm_kernel<<<8, 256, 0, stream>>>(AC, RWr, RWi, Kr, Ki);
  main_kernel<<<512, 512, 0, stream>>>(xplan, wrp, wip, AC, Kr, Ki, Wfr, Wfi, pacc);
  ln_a_kernel<<<64, 256, 0, stream>>>(pacc, y, spart);
  ln_b_kernel<<<1, 64, 0, stream>>>(spart, st);
  ln_c_kernel<<<128, 256, 0, stream>>>(y, st, g_out, b_out, out);
}